// Round 5
// baseline (3405.981 us; speedup 1.0000x reference)
//
#include <hip/hip_runtime.h>

// GRU-D fused scan, v7: MFMA edition, 16 batches/block.
// R9 diagnosis: v2-v6 all bound by the same structural tax — 105 weight
// dwords/thread can't fit the arch VGPR file, compiler parks them in AGPRs
// (or remats), and v_dot2 can't read AGPRs -> ~1 v_accvgpr_read per dot ->
// ~308 VALU/wave/step vs 105 dots, step pinned at ~3300 cyc in all variants.
// Fix: MFMA reads AGPRs for FREE. 16 batches per block (16 blocks; scan is
// latency-bound so block count is irrelevant), every matvec becomes
// mfma_f32_16x16x32_f16 with N=16 fully used. Weights = 42 A-frags pinned
// "+a" (168 AGPR/lane). C-layout (col=batch, row=4g+e) makes the gate
// update lane-local: accs r/z/ngx/ngh + h[j][b] all in-register, no preact
// LDS round-trip. h/x panels double-buffered in LDS -> ONE barrier/step.
// Skew: step i computes h0(i) (from h0(i-1), x(i)) and h1(i-1) (from
// h0(i-1), h1(i-2)) — all four matvecs read only h0(i-1), h1(i-2), x(i).

#define NBLK 16
#define BS 16
#define SS 1024
#define DD 32
#define HH 128
#define NT 512
#define XSTR 72      // x row stride in f16: 64 + 8 pad (bank spread)
#define HSTR 136     // h row stride in f16: 128 + 8 pad

typedef _Float16 f16;
typedef __attribute__((ext_vector_type(8))) _Float16 h8;
typedef __attribute__((ext_vector_type(2))) _Float16 h2;
typedef __attribute__((ext_vector_type(4))) float f4;
typedef __attribute__((ext_vector_type(4))) int i4;

__device__ inline f4 mfma16(h8 a, h8 b, f4 c) {
    return __builtin_amdgcn_mfma_f32_16x16x32_f16(a, b, c, 0, 0, 0);
}
// Pin an A-frag into AGPRs as an opaque value: not rematerializable, not
// occupying the arch file, read directly by MFMA.
__device__ inline void pinA(h8& v) {
    union { h8 h; i4 i; } u;
    u.h = v;
    asm volatile("" : "+a"(u.i));
    v = u.h;
}
__device__ inline float frcp(float x) { return __builtin_amdgcn_rcpf(x); }
__device__ inline float fast_sigm(float x) { return frcp(1.0f + __expf(-x)); }
__device__ inline float fast_tanh(float x) {
    x = fminf(15.0f, fmaxf(-15.0f, x));
    float e = __expf(-2.0f * x);
    return (1.0f - e) * frcp(1.0f + e);
}

__global__
__attribute__((amdgpu_flat_work_group_size(NT, NT), amdgpu_waves_per_eu(2, 2)))
void gru_fused(
    const float* __restrict__ t_in, const float* __restrict__ x_in,
    const float* __restrict__ Wih0, const float* __restrict__ Whh0,
    const float* __restrict__ bih0, const float* __restrict__ bhh0,
    const float* __restrict__ Wih1, const float* __restrict__ Whh1,
    const float* __restrict__ bih1, const float* __restrict__ bhh1,
    float* __restrict__ out, char* __restrict__ ws)
{
    __shared__ float tb[SS];                          // 4 KB
    __shared__ __align__(16) f16 xb[2][BS][XSTR];     // 4.5 KB  (x, dbuf)
    __shared__ __align__(16) f16 h0b[2][BS][HSTR];    // 8.5 KB  (h0, dbuf)
    __shared__ __align__(16) f16 h1b[2][BS][HSTR];    // 8.5 KB  (h1, dbuf)

    const int tid = threadIdx.x;
    const int w   = tid >> 6;      // wave 0..7: owns units [16w, 16w+16)
    const int l   = tid & 63;
    const int cb  = l & 15;        // C-frag col = batch
    const int g   = l >> 4;        // k-group (A/B) and row-group (C)
    const int blk = blockIdx.x;

    // ---- pack A-frags: lane = row (l&15)+16w of each tile, k = 32ks+8g+e ----
    h8 axf[3][2], ah0f[3][4], ax1f[3][4], ah1f[3][4];
    {
        const int arow = (l & 15) + 16 * w;
        #pragma unroll
        for (int q = 0; q < 3; q++) {          // q: 0=r rows, 1=z, 2=n
            const int row = q * 128 + arow;
            #pragma unroll
            for (int ks = 0; ks < 2; ks++) {
                h8 f;
                #pragma unroll
                for (int e = 0; e < 8; e++) {
                    int k = 32 * ks + 8 * g + e;
                    f[e] = (f16)((k < 34) ? Wih0[row * 34 + k] : 0.0f);
                }
                axf[q][ks] = f;
            }
            #pragma unroll
            for (int ks = 0; ks < 4; ks++) {
                h8 f0, f1, f2;
                #pragma unroll
                for (int e = 0; e < 8; e++) {
                    int k = 32 * ks + 8 * g + e;
                    f0[e] = (f16)Whh0[row * 128 + k];
                    f1[e] = (f16)Wih1[row * 128 + k];
                    f2[e] = (f16)Whh1[row * 128 + k];
                }
                ah0f[q][ks] = f0; ax1f[q][ks] = f1; ah1f[q][ks] = f2;
            }
        }
        #pragma unroll
        for (int q = 0; q < 3; q++) {
            pinA(axf[q][0]); pinA(axf[q][1]);
            #pragma unroll
            for (int ks = 0; ks < 4; ks++) {
                pinA(ah0f[q][ks]); pinA(ax1f[q][ks]); pinA(ah1f[q][ks]);
            }
        }
    }

    // ---- biases (f16-packed, per-lane rows j = 16w+4g+e) ----
    h2 brz[2][4], bnb[2][4];
    #pragma unroll
    for (int e = 0; e < 4; e++) {
        const int j = 16 * w + 4 * g + e;
        h2 v;
        v = h2{(f16)(bih0[j] + bhh0[j]), (f16)(bih0[j+128] + bhh0[j+128])}; brz[0][e] = v;
        v = h2{(f16)bih0[j+256], (f16)bhh0[j+256]};                          bnb[0][e] = v;
        v = h2{(f16)(bih1[j] + bhh1[j]), (f16)(bih1[j+128] + bhh1[j+128])}; brz[1][e] = v;
        v = h2{(f16)bih1[j+256], (f16)bhh1[j+256]};                          bnb[1][e] = v;
    }

    // ---- persistent h state (lane-local, matches C-layout rows/col) ----
    float hr0[4] = {0.f, 0.f, 0.f, 0.f};
    float hr1[4] = {0.f, 0.f, 0.f, 0.f};

    // ---- imputation: wave w owns batches 2w (lanes 0-31) and 2w+1 ----
    const int ib = 2 * w + (l >> 5);
    const int fx = l & 31;
    const float* xptr = x_in + ((size_t)(blk * BS + ib) * SS) * DD + fx;
    float xprev = 0.0f, tprev = 0.0f; bool hasprev = false;

    auto impute = [&](int i, float xv, int wb) {
        bool nanp = (xv != xv);
        unsigned long long bal = __ballot(nanp);
        bool m = (l < 32) ? ((bal & 0xffffffffull) != 0ull)
                          : ((bal >> 32) != 0ull);
        float imp = m ? xprev : xv;
        xb[wb][ib][fx] = (f16)imp;
        if (!m) xprev = xv;
        float tcur = tb[i];
        float tdel = (i == 0) ? 0.0f : (tcur - tb[i - 1]);
        float texp = hasprev ? (tcur - tprev) : tdel;
        if (fx == 0) {
            h2 mt = { (f16)(m ? 1.0f : 0.0f), (f16)texp };
            *(h2*)&xb[wb][ib][32] = mt;
        }
        if (!m) { hasprev = true; tprev = tcur; }
    };

    // ---- prologue: tb, zero panels, impute(0) ----
    for (int idx = tid; idx < SS; idx += NT) tb[idx] = t_in[idx];
    {
        int* z0 = (int*)&h0b[0][0][0];
        for (int idx = tid; idx < 2 * BS * HSTR / 2; idx += NT) z0[idx] = 0;
        int* z1 = (int*)&h1b[0][0][0];
        for (int idx = tid; idx < 2 * BS * HSTR / 2; idx += NT) z1[idx] = 0;
        int* z2 = (int*)&xb[0][0][0];
        for (int idx = tid; idx < 2 * BS * XSTR / 2; idx += NT) z2[idx] = 0;
    }
    __syncthreads();
    impute(0, xptr[0], 0);
    __syncthreads();

    for (int i = 0; i <= SS; ++i) {
        const int pi = i & 1;
        const bool doL0 = (i < SS), doL1 = (i > 0), doImp = (i + 1 < SS);

        // early global prefetch for next imputation (hides under MFMAs)
        float xv_n = 0.0f;
        if (doImp) xv_n = xptr[(size_t)(i + 1) * DD];

        // B-frag bases for this lane (col = cb, k-offset = 8g within kstep)
        const f16* bx  = &xb [pi    ][cb][0];   // x(i)
        const f16* bh0 = &h0b[pi ^ 1][cb][0];   // h0(i-1)
        const f16* bh1 = &h1b[pi    ][cb][0];   // h1(i-2)

        f4 aR0 = {0.f,0.f,0.f,0.f}, aZ0 = {0.f,0.f,0.f,0.f};
        f4 aX0 = {0.f,0.f,0.f,0.f}, aH0 = {0.f,0.f,0.f,0.f};
        f4 aR1 = {0.f,0.f,0.f,0.f}, aZ1 = {0.f,0.f,0.f,0.f};
        f4 aX1 = {0.f,0.f,0.f,0.f}, aH1 = {0.f,0.f,0.f,0.f};

        // x phase: gx0 -> L0 {r, z, ngx}
        #pragma unroll
        for (int ks = 0; ks < 2; ks++) {
            h8 bf = *(const h8*)(bx + 32 * ks + 8 * g);
            aR0 = mfma16(axf[0][ks], bf, aR0);
            aZ0 = mfma16(axf[1][ks], bf, aZ0);
            aX0 = mfma16(axf[2][ks], bf, aX0);
        }
        // h0 phase: gh0 -> L0 {r, z, ngh}; gx1 -> L1 {r, z, ngx}
        #pragma unroll
        for (int ks = 0; ks < 4; ks++) {
            h8 bf = *(const h8*)(bh0 + 32 * ks + 8 * g);
            aR0 = mfma16(ah0f[0][ks], bf, aR0);
            aZ0 = mfma16(ah0f[1][ks], bf, aZ0);
            aH0 = mfma16(ah0f[2][ks], bf, aH0);
            aR1 = mfma16(ax1f[0][ks], bf, aR1);
            aZ1 = mfma16(ax1f[1][ks], bf, aZ1);
            aX1 = mfma16(ax1f[2][ks], bf, aX1);
        }
        // h1 phase: gh1 -> L1 {r, z, ngh}
        #pragma unroll
        for (int ks = 0; ks < 4; ks++) {
            h8 bf = *(const h8*)(bh1 + 32 * ks + 8 * g);
            aR1 = mfma16(ah1f[0][ks], bf, aR1);
            aZ1 = mfma16(ah1f[1][ks], bf, aZ1);
            aH1 = mfma16(ah1f[2][ks], bf, aH1);
        }

        // imputation for step i+1 (overlaps MFMA drain)
        if (doImp) impute(i + 1, xv_n, pi ^ 1);

        // ---- lane-local gate updates (rows j = 16w+4g+e, batch cb) ----
        if (doL0) {
            #pragma unroll
            for (int e = 0; e < 4; e++) {
                float rr = fast_sigm(aR0[e] + (float)brz[0][e][0]);
                float zz = fast_sigm(aZ0[e] + (float)brz[0][e][1]);
                float nn = fast_tanh(aX0[e] + (float)bnb[0][e][0]
                                     + rr * (aH0[e] + (float)bnb[0][e][1]));
                hr0[e] = nn + zz * (hr0[e] - nn);
            }
            union { h2 h[2]; int2 d; } up;
            up.h[0] = h2{(f16)hr0[0], (f16)hr0[1]};
            up.h[1] = h2{(f16)hr0[2], (f16)hr0[3]};
            *(int2*)&h0b[pi][cb][16 * w + 4 * g] = up.d;   // h0(i)
        }
        if (doL1) {
            #pragma unroll
            for (int e = 0; e < 4; e++) {
                float rr = fast_sigm(aR1[e] + (float)brz[1][e][0]);
                float zz = fast_sigm(aZ1[e] + (float)brz[1][e][1]);
                float nn = fast_tanh(aX1[e] + (float)bnb[1][e][0]
                                     + rr * (aH1[e] + (float)bnb[1][e][1]));
                hr1[e] = nn + zz * (hr1[e] - nn);
            }
            union { h2 h[2]; int2 d; } up;
            up.h[0] = h2{(f16)hr1[0], (f16)hr1[1]};
            up.h[1] = h2{(f16)hr1[2], (f16)hr1[3]};
            *(int2*)&h1b[pi ^ 1][cb][16 * w + 4 * g] = up.d;  // h1(i-1)
        }
        __syncthreads();   // writes (h0(i), h1(i-1), x(i+1)) -> visible
    }

    // hr1 = h1(SS-1): final hidden of layer 1
    float* op = out + (size_t)(blk * BS + cb) * HH + 16 * w + 4 * g;
    #pragma unroll
    for (int e = 0; e < 4; e++) op[e] = hr1[e];
}

extern "C" void kernel_launch(void* const* d_in, const int* in_sizes, int n_in,
                              void* d_out, int out_size, void* d_ws, size_t ws_size,
                              hipStream_t stream) {
    gru_fused<<<dim3(NBLK), dim3(NT), 0, stream>>>(
        (const float*)d_in[0], (const float*)d_in[1],
        (const float*)d_in[2], (const float*)d_in[3],
        (const float*)d_in[4], (const float*)d_in[5],
        (const float*)d_in[6], (const float*)d_in[7],
        (const float*)d_in[8], (const float*)d_in[9],
        (float*)d_out, (char*)d_ws);
}